// Round 13
// baseline (288.303 us; speedup 1.0000x reference)
//
#include <hip/hip_runtime.h>
#include <stdint.h>

// ---------------------------------------------------------------------------
// UserSpotConv: bipartite GCN aggregation.
//   user_out[u] = isd_u[u] * sum_{e: u_e=u} spot_x[s_e] * isd_s[s_e]
//   spot_out[s] = isd_s[s] * sum_{e: s_e=s} user_x[u_e] * isd_u[u_e]
// Round 13 = round 12 with the part2 edit-artifact bug removed (a stray
// `dltU[0] = 0` executed in both dir-iterations, zeroing U-bucket-0's flush
// offset after it was computed -> absmax 0.9). Design unchanged:
//   part2 slim-LDS (28.7 KB, 5 blocks/CU): cur doubles as hist; gbase/loff
//   folded into dlt[b] = atomicAdd(gc,h) - local_base; flush out[dlt[b]+k].
//   bsort3b 512 threads. cscan untouched (58.6 us/dir = proven fetch floor).
// ---------------------------------------------------------------------------

#define NPB_LOG2 6
#define NPB 64             // destination nodes per bucket
#define MAXB 768           // max buckets per direction
#define PART_CHUNK 2048    // edges per block in part2_kernel
#define BH_CHUNK 16384     // edges per block in bhist_kernel
#define SORT_CAP 8192      // max edges per bucket for bsort staging
#define CSCAN_CH 256       // edges per wave in cscan

__device__ __forceinline__ ushort f2bf(float f) {
    uint32_t u = __float_as_uint(f);
    return (ushort)((u + 0x7fffu + ((u >> 16) & 1u)) >> 16);  // RNE
}

// Bucket-level histogram for BOTH directions in one pass.
__global__ __launch_bounds__(256) void bhist_kernel(
        const int* __restrict__ u, const int* __restrict__ s, int E,
        int nbu, int nbs, int* __restrict__ bd) {
    __shared__ int hist[2 * MAXB];
    const int tid = threadIdx.x;
    const int nb = nbu + nbs;
    const int beg = blockIdx.x * BH_CHUNK;
    const int end = min(beg + BH_CHUNK, E);
    for (int b = tid; b < nb; b += 256) hist[b] = 0;
    __syncthreads();
    for (int i = beg + tid; i < end; i += 256) {
        atomicAdd(&hist[u[i] >> NPB_LOG2], 1);
        atomicAdd(&hist[nbu + (s[i] >> NPB_LOG2)], 1);
    }
    __syncthreads();
    for (int b = tid; b < nb; b += 256) {
        int h = hist[b];
        if (h) atomicAdd(&bd[b], h);
    }
}

// Fused dual exclusive scan (block 0: u-buckets, block 1: s-buckets) that
// also initializes the part2 global cursors. n <= 1024 (MAXB=768).
__global__ __launch_bounds__(1024) void scan2_kernel(
        const int* __restrict__ bd, int nbu, int nbs,
        int* __restrict__ buoff, int* __restrict__ bsoff,
        int* __restrict__ gcu, int* __restrict__ gcs) {
    __shared__ int wsums[16];
    __shared__ int total;
    const int tid = threadIdx.x, lane = tid & 63, wid = tid >> 6;
    const int n   = blockIdx.x ? nbs : nbu;
    const int* in = blockIdx.x ? (bd + nbu) : bd;
    int* out = blockIdx.x ? bsoff : buoff;
    int* gc  = blockIdx.x ? gcs   : gcu;
    int v = (tid < n) ? in[tid] : 0;
    int x = v;
#pragma unroll
    for (int d = 1; d < 64; d <<= 1) {
        int t = __shfl_up(x, d);
        if (lane >= d) x += t;
    }
    if (lane == 63) wsums[wid] = x;
    __syncthreads();
    if (tid == 0) {
        int run = 0;
#pragma unroll
        for (int w = 0; w < 16; ++w) { int t = wsums[w]; wsums[w] = run; run += t; }
        total = run;
    }
    __syncthreads();
    int excl = wsums[wid] + (x - v);
    if (tid < n) { out[tid] = excl; gc[tid] = excl; }
    if (tid == 0) out[n] = total;
}

// xb row layout is PERMUTED: slot 2c holds col c, slot 2c+1 holds col c+64,
// so a lane's uint32 load at byte row*256+4*l yields cols (l, l+64).
// convert2: both tables in one dispatch.
__global__ void convert2_kernel(const float* __restrict__ spot_x,
                                const float* __restrict__ user_x,
                                const float* __restrict__ isd_s,
                                const float* __restrict__ isd_u,
                                ushort* __restrict__ xbs, ushort* __restrict__ xbu,
                                int M, int N) {
    int idx = blockIdx.x * blockDim.x + threadIdx.x;
    if (idx >= ((M + N) << 6)) return;
    int row = idx >> 6, c = idx & 63;
    const float* x; float w; ushort* xb;
    if (row < M) { x = spot_x + ((size_t)row << 7); w = isd_s[row]; xb = xbs + ((size_t)row << 7); }
    else { row -= M; x = user_x + ((size_t)row << 7); w = isd_u[row]; xb = xbu + ((size_t)row << 7); }
    ushort2 o;
    o.x = f2bf(x[c] * w);
    o.y = f2bf(x[c + 64] * w);
    *reinterpret_cast<ushort2*>(xb + 2 * c) = o;
}

// Single-table convert (tier B).
__global__ void convert_kernel(const float* __restrict__ x, const float* __restrict__ isd,
                               ushort* __restrict__ xb, int n_rows) {
    int idx = blockIdx.x * blockDim.x + threadIdx.x;
    if (idx >= (n_rows << 6)) return;
    int row = idx >> 6, c = idx & 63;
    float w = isd[row];
    const float* xr = x + ((size_t)row << 7);
    ushort2 o;
    o.x = f2bf(xr[c] * w);
    o.y = f2bf(xr[c + 64] * w);
    *reinterpret_cast<ushort2*>(xb + ((size_t)row << 7) + 2 * c) = o;
}

// Both-direction partition, slim-LDS version (28.7 KB -> 5 blocks/CU).
// cur doubles as hist (threads read their own buckets into regs before
// overwrite); flush uses dlt[b] = global_base - local_base so neither
// gbase nor loff arrays are needed.
__global__ __launch_bounds__(256) void part2_kernel(
        const int* __restrict__ u, const int* __restrict__ s, int E,
        int nbu, int nbs, int* __restrict__ gcu, int* __restrict__ gcs,
        uint32_t* __restrict__ outU, uint32_t* __restrict__ outS) {
    __shared__ int curU[MAXB], dltU[MAXB];
    __shared__ int curS[MAXB], dltS[MAXB];
    __shared__ int wsum[4];
    __shared__ uint32_t sbufU[PART_CHUNK];
    __shared__ uint32_t sbufS[PART_CHUNK];
    const int tid = threadIdx.x;
    const int lane = tid & 63;
    const int wid = tid >> 6;
    const int beg = blockIdx.x * PART_CHUNK;
    const int end = min(beg + PART_CHUNK, E);
    const int cnt_total = end - beg;
    for (int b = tid; b < nbu; b += 256) curU[b] = 0;   // cur as hist
    for (int b = tid; b < nbs; b += 256) curS[b] = 0;
    __syncthreads();
    for (int i = beg + tid; i < end; i += 256) {
        atomicAdd(&curU[u[i] >> NPB_LOG2], 1);
        atomicAdd(&curS[s[i] >> NPB_LOG2], 1);
    }
    __syncthreads();
    // per dir: scan hist (3 buckets/thread, values held in regs), then
    // cur[b] := local exclusive base, dlt[b] := global base - local base.
    for (int dir = 0; dir < 2; ++dir) {
        int nb   = dir ? nbs  : nbu;
        int* cur = dir ? curS : curU;
        int* dlt = dir ? dltS : dltU;
        int* gc  = dir ? gcs  : gcu;
        int b0 = tid * 3;
        int h0 = (b0 + 0 < nb) ? cur[b0 + 0] : 0;
        int h1 = (b0 + 1 < nb) ? cur[b0 + 1] : 0;
        int h2 = (b0 + 2 < nb) ? cur[b0 + 2] : 0;
        int tsum = h0 + h1 + h2;
        int x = tsum;
#pragma unroll
        for (int d = 1; d < 64; d <<= 1) {
            int t = __shfl_up(x, d);
            if (lane >= d) x += t;
        }
        if (lane == 63) wsum[wid] = x;
        __syncthreads();
        if (tid == 0) {
            int run = 0;
#pragma unroll
            for (int w = 0; w < 4; ++w) { int t = wsum[w]; wsum[w] = run; run += t; }
        }
        __syncthreads();
        int base = wsum[wid] + (x - tsum);
        int l0 = base, l1 = base + h0, l2 = base + h0 + h1;
        if (b0 + 0 < nb) { cur[b0 + 0] = l0; if (h0) dlt[b0 + 0] = atomicAdd(&gc[b0 + 0], h0) - l0; }
        if (b0 + 1 < nb) { cur[b0 + 1] = l1; if (h1) dlt[b0 + 1] = atomicAdd(&gc[b0 + 1], h1) - l1; }
        if (b0 + 2 < nb) { cur[b0 + 2] = l2; if (h2) dlt[b0 + 2] = atomicAdd(&gc[b0 + 2], h2) - l2; }
        __syncthreads();
    }
    for (int i = beg + tid; i < end; i += 256) {
        int uu = u[i], ss = s[i];
        int lu = atomicAdd(&curU[uu >> NPB_LOG2], 1);
        sbufU[lu] = ((uint32_t)uu << 16) | (uint32_t)ss;
        int ls = atomicAdd(&curS[ss >> NPB_LOG2], 1);
        sbufS[ls] = ((uint32_t)ss << 16) | (uint32_t)uu;
    }
    __syncthreads();
    for (int k = tid; k < cnt_total; k += 256) {
        uint32_t p = sbufU[k];
        outU[dltU[p >> (16 + NPB_LOG2)] + k] = p;
        uint32_t q = sbufS[k];
        outS[dltS[q >> (16 + NPB_LOG2)] + k] = q;
    }
}

// Combined-direction per-bucket counting sort by dst, in place (LDS-staged),
// AND write isd = rsqrt(degree). 512 threads (8 waves) for latency hiding.
__global__ __launch_bounds__(512) void bsort3b_kernel(
        uint32_t* __restrict__ bufU, uint32_t* __restrict__ bufS,
        const int* __restrict__ buoff, const int* __restrict__ bsoff, int nbu,
        float* __restrict__ isd_u, float* __restrict__ isd_s, int N, int M) {
    __shared__ uint32_t stage[SORT_CAP];
    __shared__ int hist[NPB];
    __shared__ int cur[NPB];
    const int tid = threadIdx.x;
    const int b = blockIdx.x;
    uint32_t* buf; const int* boff; float* isd; int n_rows; int bb;
    if (b < nbu) { buf = bufU; boff = buoff; isd = isd_u; n_rows = N; bb = b; }
    else         { buf = bufS; boff = bsoff; isd = isd_s; n_rows = M; bb = b - nbu; }
    const int jbeg = boff[bb];
    const int cnt = boff[bb + 1] - jbeg;
    const bool fits = (cnt <= SORT_CAP);   // sort perf-only; isd always written
    if (tid < NPB) hist[tid] = 0;
    __syncthreads();
    for (int k = tid; k < cnt; k += 512) {
        uint32_t p = buf[jbeg + k];
        if (fits) stage[k] = p;
        atomicAdd(&hist[(p >> 16) & (NPB - 1)], 1);
    }
    __syncthreads();   // drains global reads before in-place overwrite
    if (tid < NPB) {   // wave 0: 64-wide exclusive scan via shfl + isd write
        int h = hist[tid];
        int x = h;
#pragma unroll
        for (int d = 1; d < 64; d <<= 1) {
            int t = __shfl_up(x, d);
            if (tid >= d) x += t;
        }
        cur[tid] = x - h;
        int node = (bb << NPB_LOG2) + tid;
        if (node < n_rows) isd[node] = h > 0 ? rsqrtf((float)h) : 0.f;
    }
    __syncthreads();
    if (fits) {
        for (int k = tid; k < cnt; k += 512) {
            uint32_t p = stage[k];
            int slot = atomicAdd(&cur[(p >> 16) & (NPB - 1)], 1);
            buf[jbeg + slot] = p;
        }
    }
}

// Wave per CSCAN_CH consecutive dst-sorted edges; register accumulate,
// flush on dst change via native f32 atomic. (Proven 58.6us/dir — the
// fetch floor of this decomposition; r8/r9/r10 restructures all lost.)
__global__ __launch_bounds__(256) void cscan_kernel(
        const ushort* __restrict__ xb, const uint32_t* __restrict__ packed, int E,
        const float* __restrict__ isd, float* __restrict__ out) {
    const int lane = threadIdx.x & 63;
    const int wave = (blockIdx.x << 2) + (threadIdx.x >> 6);
    const int base = wave * CSCAN_CH;
    if (base >= E) return;
    const int n = min(CSCAN_CH, E - base);
    const uint32_t* pp = packed + base;
    float ax = 0.f, ay = 0.f;
    int cur = (int)(pp[0] >> 16);

#define ROW(pv) (*reinterpret_cast<const uint32_t*>( \
        xb + (((size_t)((pv) & 0xffffu)) << 7) + (lane << 1)))
#define UPX(rv) __uint_as_float((rv) << 16)
#define UPY(rv) __uint_as_float((rv) & 0xffff0000u)
#define FLUSH() do { float w_ = isd[cur];                                  \
        unsafeAtomicAdd(out + ((size_t)cur << 7) + lane, ax * w_);         \
        unsafeAtomicAdd(out + ((size_t)cur << 7) + 64 + lane, ay * w_);    \
        ax = 0.f; ay = 0.f; } while (0)
#define PROC(pv, rv) do { int d_ = (int)((pv) >> 16);                      \
        if (d_ != cur) { FLUSH(); cur = d_; }                              \
        ax += UPX(rv); ay += UPY(rv); } while (0)
#define GRP8(Aa, Ab, r0, r1, r2, r3, r4, r5, r6, r7) do {                  \
    if ((((Aa.x ^ Ab.w) >> 16) == 0) && ((int)(Aa.x >> 16) == cur)) {      \
        float sx = ((UPX(r0) + UPX(r1)) + (UPX(r2) + UPX(r3)))             \
                 + ((UPX(r4) + UPX(r5)) + (UPX(r6) + UPX(r7)));            \
        float sy = ((UPY(r0) + UPY(r1)) + (UPY(r2) + UPY(r3)))             \
                 + ((UPY(r4) + UPY(r5)) + (UPY(r6) + UPY(r7)));            \
        ax += sx; ay += sy;                                                \
    } else {                                                               \
        PROC(Aa.x, r0); PROC(Aa.y, r1); PROC(Aa.z, r2); PROC(Aa.w, r3);    \
        PROC(Ab.x, r4); PROC(Ab.y, r5); PROC(Ab.z, r6); PROC(Ab.w, r7);    \
    } } while (0)

    int k = 0;
    if (n >= 24) {
        uint4 P0a = *(const uint4*)(pp + 0),  P0b = *(const uint4*)(pp + 4);
        uint4 P1a = *(const uint4*)(pp + 8),  P1b = *(const uint4*)(pp + 12);
        uint32_t a0 = ROW(P0a.x), a1 = ROW(P0a.y), a2 = ROW(P0a.z), a3 = ROW(P0a.w),
                 a4 = ROW(P0b.x), a5 = ROW(P0b.y), a6 = ROW(P0b.z), a7 = ROW(P0b.w);
        uint4 P2a = *(const uint4*)(pp + 16), P2b = *(const uint4*)(pp + 20);
        uint32_t b0 = ROW(P1a.x), b1 = ROW(P1a.y), b2 = ROW(P1a.z), b3 = ROW(P1a.w),
                 b4 = ROW(P1b.x), b5 = ROW(P1b.y), b6 = ROW(P1b.z), b7 = ROW(P1b.w);
        for (k = 24; k + 8 <= n; k += 8) {
            uint4 P3a = *(const uint4*)(pp + k), P3b = *(const uint4*)(pp + k + 4);
            uint32_t c0 = ROW(P2a.x), c1 = ROW(P2a.y), c2 = ROW(P2a.z), c3 = ROW(P2a.w),
                     c4 = ROW(P2b.x), c5 = ROW(P2b.y), c6 = ROW(P2b.z), c7 = ROW(P2b.w);
            GRP8(P0a, P0b, a0, a1, a2, a3, a4, a5, a6, a7);
            P0a = P1a; P0b = P1b; P1a = P2a; P1b = P2b; P2a = P3a; P2b = P3b;
            a0 = b0; a1 = b1; a2 = b2; a3 = b3; a4 = b4; a5 = b5; a6 = b6; a7 = b7;
            b0 = c0; b1 = c1; b2 = c2; b3 = c3; b4 = c4; b5 = c5; b6 = c6; b7 = c7;
        }
        uint32_t c0 = ROW(P2a.x), c1 = ROW(P2a.y), c2 = ROW(P2a.z), c3 = ROW(P2a.w),
                 c4 = ROW(P2b.x), c5 = ROW(P2b.y), c6 = ROW(P2b.z), c7 = ROW(P2b.w);
        GRP8(P0a, P0b, a0, a1, a2, a3, a4, a5, a6, a7);
        GRP8(P1a, P1b, b0, b1, b2, b3, b4, b5, b6, b7);
        GRP8(P2a, P2b, c0, c1, c2, c3, c4, c5, c6, c7);
    }
    for (; k < n; ++k) {
        uint32_t p = pp[k];
        uint32_t r = ROW(p);
        PROC(p, r);
    }
    FLUSH();
#undef GRP8
#undef PROC
#undef FLUSH
#undef UPY
#undef UPX
#undef ROW
}

// ---- minimal-ws fallback ---------------------------------------------------

__global__ void deg_kernel(const int* __restrict__ u, const int* __restrict__ s,
                           int E, int* __restrict__ udeg, int* __restrict__ sdeg) {
    int i = blockIdx.x * blockDim.x + threadIdx.x;
    if (i < E) {
        atomicAdd(&udeg[u[i]], 1);
        atomicAdd(&sdeg[s[i]], 1);
    }
}

__global__ void init_isd_kernel(const int* __restrict__ udeg, const int* __restrict__ sdeg,
                                float* __restrict__ isd_u, float* __restrict__ isd_s,
                                int n_user, int m_spot) {
    int i = blockIdx.x * blockDim.x + threadIdx.x;
    if (i < n_user) { int d = udeg[i]; isd_u[i] = d > 0 ? rsqrtf((float)d) : 0.f; }
    if (i < m_spot) { int d = sdeg[i]; isd_s[i] = d > 0 ? rsqrtf((float)d) : 0.f; }
}

__global__ __launch_bounds__(256) void scatter_kernel(const float* __restrict__ spot_x,
                                                      const float* __restrict__ user_x,
                                                      const int* __restrict__ u,
                                                      const int* __restrict__ s, int E,
                                                      const float* __restrict__ isd_u,
                                                      const float* __restrict__ isd_s,
                                                      float* __restrict__ spot_out,
                                                      float* __restrict__ user_out) {
    const int lane = threadIdx.x & 63;
    const int e = blockIdx.x * 4 + (threadIdx.x >> 6);
    if (e >= E) return;
    const int uu = u[e], ss = s[e];
    const float w = isd_u[uu] * isd_s[ss];
    const float2 sv = *reinterpret_cast<const float2*>(spot_x + (size_t)ss * 128 + lane * 2);
    const float2 uv = *reinterpret_cast<const float2*>(user_x + (size_t)uu * 128 + lane * 2);
    atomicAdd(&user_out[(size_t)uu * 128 + lane * 2 + 0], sv.x * w);
    atomicAdd(&user_out[(size_t)uu * 128 + lane * 2 + 1], sv.y * w);
    atomicAdd(&spot_out[(size_t)ss * 128 + lane * 2 + 0], uv.x * w);
    atomicAdd(&spot_out[(size_t)ss * 128 + lane * 2 + 1], uv.y * w);
}

static inline char* align256(char* p) {
    return (char*)(((uintptr_t)p + 255u) & ~(uintptr_t)255u);
}

extern "C" void kernel_launch(void* const* d_in, const int* in_sizes, int n_in,
                              void* d_out, int out_size, void* d_ws, size_t ws_size,
                              hipStream_t stream) {
    const float* spot_x = (const float*)d_in[0];
    const float* user_x = (const float*)d_in[1];
    const int*   edges  = (const int*)d_in[2];
    const int M = in_sizes[0] / 128;   // spots
    const int N = in_sizes[1] / 128;   // users
    const int E = in_sizes[2] / 2;
    const int* u = edges;        // user_spot[0]
    const int* s = edges + E;    // user_spot[1]
    float* spot_out = (float*)d_out;
    float* user_out = (float*)d_out + (size_t)M * 128;

    const int nbu = (N + NPB - 1) / NPB;
    const int nbs = (M + NPB - 1) / NPB;
    const int nm = (N > M) ? N : M;
    const int gpart = (E + PART_CHUNK - 1) / PART_CHUNK;
    const int gscan = ((E + CSCAN_CH - 1) / CSCAN_CH + 3) / 4;

    // Common metadata layout (shared by tiers A and B).
    char* ws = (char*)d_ws;
    float*    isd_u = (float*)ws; ws = align256(ws + sizeof(float) * (size_t)N);
    float*    isd_s = (float*)ws; ws = align256(ws + sizeof(float) * (size_t)M);
    int*      bd    = (int*)ws;   ws = align256(ws + sizeof(int) * (size_t)(nbu + nbs));
    int*      buoff = (int*)ws;   ws = align256(ws + sizeof(int) * (size_t)(nbu + 1));
    int*      bsoff = (int*)ws;   ws = align256(ws + sizeof(int) * (size_t)(nbs + 1));
    int*      gcu   = (int*)ws;   ws = align256(ws + sizeof(int) * (size_t)nbu);
    int*      gcs   = (int*)ws;   ws = align256(ws + sizeof(int) * (size_t)nbs);
    uint32_t* bufU  = (uint32_t*)ws; ws = align256(ws + sizeof(uint32_t) * (size_t)E);
    uint32_t* bufS  = (uint32_t*)ws; ws = align256(ws + sizeof(uint32_t) * (size_t)E);
    ushort*   xbs   = (ushort*)ws;   // tier A: spot table (tier B: union slot)
    ushort*   xbu   = (ushort*)align256((char*)xbs + sizeof(ushort) * ((size_t)M * 128));
    size_t tierA_needed = (size_t)((char*)xbu - (char*)d_ws)
                        + sizeof(ushort) * ((size_t)N * 128);
    size_t tierB_needed = (size_t)((char*)xbs - (char*)d_ws)
                        + sizeof(ushort) * ((size_t)nm * 128);

    if (tierB_needed <= ws_size && nbu <= MAXB && nbs <= MAXB) {
        hipMemsetAsync(bd, 0, sizeof(int) * (size_t)(nbu + nbs), stream);
        hipMemsetAsync(d_out, 0, sizeof(float) * (size_t)out_size, stream);
        bhist_kernel<<<(E + BH_CHUNK - 1) / BH_CHUNK, 256, 0, stream>>>(
            u, s, E, nbu, nbs, bd);
        scan2_kernel<<<2, 1024, 0, stream>>>(bd, nbu, nbs, buoff, bsoff, gcu, gcs);
        part2_kernel<<<gpart, 256, 0, stream>>>(u, s, E, nbu, nbs, gcu, gcs, bufU, bufS);
        bsort3b_kernel<<<nbu + nbs, 512, 0, stream>>>(
            bufU, bufS, buoff, bsoff, nbu, isd_u, isd_s, N, M);
        if (tierA_needed <= ws_size) {
            // ---- tier A: both tables resident, sequential cscans ---------
            convert2_kernel<<<(((M + N) << 6) + 255) / 256, 256, 0, stream>>>(
                spot_x, user_x, isd_s, isd_u, xbs, xbu, M, N);
            cscan_kernel<<<gscan, 256, 0, stream>>>(xbs, bufU, E, isd_u, user_out);
            cscan_kernel<<<gscan, 256, 0, stream>>>(xbu, bufS, E, isd_s, spot_out);
        } else {
            // ---- tier B: union table slot, sequential --------------------
            ushort* xb = xbs;
            convert_kernel<<<((M << 6) + 255) / 256, 256, 0, stream>>>(spot_x, isd_s, xb, M);
            cscan_kernel<<<gscan, 256, 0, stream>>>(xb, bufU, E, isd_u, user_out);
            convert_kernel<<<((N << 6) + 255) / 256, 256, 0, stream>>>(user_x, isd_u, xb, N);
            cscan_kernel<<<gscan, 256, 0, stream>>>(xb, bufS, E, isd_s, spot_out);
        }
        return;
    }

    // ---- minimal-ws fallback: degree + atomic scatter ----------------------
    {
        char* w2 = (char*)d_ws;
        int*   udeg2  = (int*)w2;   w2 += sizeof(int) * (size_t)N;
        int*   sdeg2  = (int*)w2;   w2 += sizeof(int) * (size_t)M;
        float* isd_u2 = (float*)w2; w2 += sizeof(float) * (size_t)N;
        float* isd_s2 = (float*)w2; w2 += sizeof(float) * (size_t)M;
        if ((size_t)(w2 - (char*)d_ws) <= ws_size) {
            hipMemsetAsync(udeg2, 0, sizeof(int) * (size_t)(N + M), stream);
            deg_kernel<<<(E + 255) / 256, 256, 0, stream>>>(u, s, E, udeg2, sdeg2);
            init_isd_kernel<<<(nm + 255) / 256, 256, 0, stream>>>(
                udeg2, sdeg2, isd_u2, isd_s2, N, M);
            hipMemsetAsync(d_out, 0, sizeof(float) * (size_t)out_size, stream);
            scatter_kernel<<<((size_t)E + 3) / 4, 256, 0, stream>>>(
                spot_x, user_x, u, s, E, isd_u2, isd_s2, spot_out, user_out);
        }
    }
}

// Round 14
// 236.119 us; speedup vs baseline: 1.2210x; 1.2210x over previous
//
#include <hip/hip_runtime.h>
#include <stdint.h>

// ---------------------------------------------------------------------------
// UserSpotConv: bipartite GCN aggregation.
//   user_out[u] = isd_u[u] * sum_{e: u_e=u} spot_x[s_e] * isd_s[s_e]
//   spot_out[s] = isd_s[s] * sum_{e: s_e=s} user_x[u_e] * isd_u[u_e]
// Round 14 (revert/consolidate): r13's slim-LDS part2 regressed 59.7->112.6us
// (occupancy rose 25->40% but VALUBusy fell 4.4->2.2% — part2 is global-
// cursor-atomic-latency bound, and the slim rewrite serialized the two
// directions' atomic waits behind barriers). Revert to r11's proven part2
// verbatim. Keep bsort3b@512 (measured neutral). cscan untouched
// (58.6 us/dir = the established fetch floor of this decomposition).
// Best-known pipeline: memset -> bhist -> scan2 -> part2 -> bsort3b ->
// convert2 -> cscan_u -> cscan_s  (~238 us).
// ---------------------------------------------------------------------------

#define NPB_LOG2 6
#define NPB 64             // destination nodes per bucket
#define MAXB 768           // max buckets per direction
#define PART_CHUNK 2048    // edges per block in part2_kernel
#define BH_CHUNK 16384     // edges per block in bhist_kernel
#define SORT_CAP 8192      // max edges per bucket for bsort staging
#define CSCAN_CH 256       // edges per wave in cscan

__device__ __forceinline__ ushort f2bf(float f) {
    uint32_t u = __float_as_uint(f);
    return (ushort)((u + 0x7fffu + ((u >> 16) & 1u)) >> 16);  // RNE
}

// Bucket-level histogram for BOTH directions in one pass.
__global__ __launch_bounds__(256) void bhist_kernel(
        const int* __restrict__ u, const int* __restrict__ s, int E,
        int nbu, int nbs, int* __restrict__ bd) {
    __shared__ int hist[2 * MAXB];
    const int tid = threadIdx.x;
    const int nb = nbu + nbs;
    const int beg = blockIdx.x * BH_CHUNK;
    const int end = min(beg + BH_CHUNK, E);
    for (int b = tid; b < nb; b += 256) hist[b] = 0;
    __syncthreads();
    for (int i = beg + tid; i < end; i += 256) {
        atomicAdd(&hist[u[i] >> NPB_LOG2], 1);
        atomicAdd(&hist[nbu + (s[i] >> NPB_LOG2)], 1);
    }
    __syncthreads();
    for (int b = tid; b < nb; b += 256) {
        int h = hist[b];
        if (h) atomicAdd(&bd[b], h);
    }
}

// Fused dual exclusive scan (block 0: u-buckets, block 1: s-buckets) that
// also initializes the part2 global cursors. n <= 1024 (MAXB=768).
__global__ __launch_bounds__(1024) void scan2_kernel(
        const int* __restrict__ bd, int nbu, int nbs,
        int* __restrict__ buoff, int* __restrict__ bsoff,
        int* __restrict__ gcu, int* __restrict__ gcs) {
    __shared__ int wsums[16];
    __shared__ int total;
    const int tid = threadIdx.x, lane = tid & 63, wid = tid >> 6;
    const int n   = blockIdx.x ? nbs : nbu;
    const int* in = blockIdx.x ? (bd + nbu) : bd;
    int* out = blockIdx.x ? bsoff : buoff;
    int* gc  = blockIdx.x ? gcs   : gcu;
    int v = (tid < n) ? in[tid] : 0;
    int x = v;
#pragma unroll
    for (int d = 1; d < 64; d <<= 1) {
        int t = __shfl_up(x, d);
        if (lane >= d) x += t;
    }
    if (lane == 63) wsums[wid] = x;
    __syncthreads();
    if (tid == 0) {
        int run = 0;
#pragma unroll
        for (int w = 0; w < 16; ++w) { int t = wsums[w]; wsums[w] = run; run += t; }
        total = run;
    }
    __syncthreads();
    int excl = wsums[wid] + (x - v);
    if (tid < n) { out[tid] = excl; gc[tid] = excl; }
    if (tid == 0) out[n] = total;
}

// xb row layout is PERMUTED: slot 2c holds col c, slot 2c+1 holds col c+64,
// so a lane's uint32 load at byte row*256+4*l yields cols (l, l+64).
// convert2: both tables in one dispatch.
__global__ void convert2_kernel(const float* __restrict__ spot_x,
                                const float* __restrict__ user_x,
                                const float* __restrict__ isd_s,
                                const float* __restrict__ isd_u,
                                ushort* __restrict__ xbs, ushort* __restrict__ xbu,
                                int M, int N) {
    int idx = blockIdx.x * blockDim.x + threadIdx.x;
    if (idx >= ((M + N) << 6)) return;
    int row = idx >> 6, c = idx & 63;
    const float* x; float w; ushort* xb;
    if (row < M) { x = spot_x + ((size_t)row << 7); w = isd_s[row]; xb = xbs + ((size_t)row << 7); }
    else { row -= M; x = user_x + ((size_t)row << 7); w = isd_u[row]; xb = xbu + ((size_t)row << 7); }
    ushort2 o;
    o.x = f2bf(x[c] * w);
    o.y = f2bf(x[c + 64] * w);
    *reinterpret_cast<ushort2*>(xb + 2 * c) = o;
}

// Single-table convert (tier B).
__global__ void convert_kernel(const float* __restrict__ x, const float* __restrict__ isd,
                               ushort* __restrict__ xb, int n_rows) {
    int idx = blockIdx.x * blockDim.x + threadIdx.x;
    if (idx >= (n_rows << 6)) return;
    int row = idx >> 6, c = idx & 63;
    float w = isd[row];
    const float* xr = x + ((size_t)row << 7);
    ushort2 o;
    o.x = f2bf(xr[c] * w);
    o.y = f2bf(xr[c + 64] * w);
    *reinterpret_cast<ushort2*>(xb + ((size_t)row << 7) + 2 * c) = o;
}

// Both-direction partition in ONE kernel (r11-proven version): reads each
// edge once, stages both (u<<16|s) and (s<<16|u) into LDS bucket-ordered,
// element-parallel coalesced run flush.
__global__ __launch_bounds__(256) void part2_kernel(
        const int* __restrict__ u, const int* __restrict__ s, int E,
        int nbu, int nbs, int* __restrict__ gcu, int* __restrict__ gcs,
        uint32_t* __restrict__ outU, uint32_t* __restrict__ outS) {
    __shared__ int histU[MAXB], loffU[MAXB], gbaseU[MAXB], curU[MAXB];
    __shared__ int histS[MAXB], loffS[MAXB], gbaseS[MAXB], curS[MAXB];
    __shared__ int wsum[4];
    __shared__ uint32_t sbufU[PART_CHUNK];
    __shared__ uint32_t sbufS[PART_CHUNK];
    const int tid = threadIdx.x;
    const int lane = tid & 63;
    const int wid = tid >> 6;
    const int beg = blockIdx.x * PART_CHUNK;
    const int end = min(beg + PART_CHUNK, E);
    const int cnt_total = end - beg;
    for (int b = tid; b < nbu; b += 256) histU[b] = 0;
    for (int b = tid; b < nbs; b += 256) histS[b] = 0;
    __syncthreads();
    for (int i = beg + tid; i < end; i += 256) {
        atomicAdd(&histU[u[i] >> NPB_LOG2], 1);
        atomicAdd(&histS[s[i] >> NPB_LOG2], 1);
    }
    __syncthreads();
    for (int dir = 0; dir < 2; ++dir) {
        int nb = dir ? nbs : nbu;
        int* hist = dir ? histS : histU;
        int* loff = dir ? loffS : loffU;
        int b0 = tid * 3;
        int h0 = (b0 + 0 < nb) ? hist[b0 + 0] : 0;
        int h1 = (b0 + 1 < nb) ? hist[b0 + 1] : 0;
        int h2 = (b0 + 2 < nb) ? hist[b0 + 2] : 0;
        int tsum = h0 + h1 + h2;
        int x = tsum;
#pragma unroll
        for (int d = 1; d < 64; d <<= 1) {
            int t = __shfl_up(x, d);
            if (lane >= d) x += t;
        }
        if (lane == 63) wsum[wid] = x;
        __syncthreads();
        if (tid == 0) {
            int run = 0;
#pragma unroll
            for (int w = 0; w < 4; ++w) { int t = wsum[w]; wsum[w] = run; run += t; }
        }
        __syncthreads();
        int base = wsum[wid] + (x - tsum);
        if (b0 + 0 < nb) loff[b0 + 0] = base;
        if (b0 + 1 < nb) loff[b0 + 1] = base + h0;
        if (b0 + 2 < nb) loff[b0 + 2] = base + h0 + h1;
        __syncthreads();
    }
    for (int b = tid; b < nbu; b += 256) {
        curU[b] = loffU[b];
        int c = histU[b];
        gbaseU[b] = c > 0 ? atomicAdd(&gcu[b], c) : 0;
    }
    for (int b = tid; b < nbs; b += 256) {
        curS[b] = loffS[b];
        int c = histS[b];
        gbaseS[b] = c > 0 ? atomicAdd(&gcs[b], c) : 0;
    }
    __syncthreads();
    for (int i = beg + tid; i < end; i += 256) {
        int uu = u[i], ss = s[i];
        int lu = atomicAdd(&curU[uu >> NPB_LOG2], 1);
        sbufU[lu] = ((uint32_t)uu << 16) | (uint32_t)ss;
        int ls = atomicAdd(&curS[ss >> NPB_LOG2], 1);
        sbufS[ls] = ((uint32_t)ss << 16) | (uint32_t)uu;
    }
    __syncthreads();
    for (int k = tid; k < cnt_total; k += 256) {
        uint32_t p = sbufU[k];
        int b = (int)(p >> (16 + NPB_LOG2));
        outU[gbaseU[b] + (k - loffU[b])] = p;
        uint32_t q = sbufS[k];
        int b2 = (int)(q >> (16 + NPB_LOG2));
        outS[gbaseS[b2] + (k - loffS[b2])] = q;
    }
}

// Combined-direction per-bucket counting sort by dst, in place (LDS-staged),
// AND write isd = rsqrt(degree). 512 threads (8 waves) for latency hiding.
__global__ __launch_bounds__(512) void bsort3b_kernel(
        uint32_t* __restrict__ bufU, uint32_t* __restrict__ bufS,
        const int* __restrict__ buoff, const int* __restrict__ bsoff, int nbu,
        float* __restrict__ isd_u, float* __restrict__ isd_s, int N, int M) {
    __shared__ uint32_t stage[SORT_CAP];
    __shared__ int hist[NPB];
    __shared__ int cur[NPB];
    const int tid = threadIdx.x;
    const int b = blockIdx.x;
    uint32_t* buf; const int* boff; float* isd; int n_rows; int bb;
    if (b < nbu) { buf = bufU; boff = buoff; isd = isd_u; n_rows = N; bb = b; }
    else         { buf = bufS; boff = bsoff; isd = isd_s; n_rows = M; bb = b - nbu; }
    const int jbeg = boff[bb];
    const int cnt = boff[bb + 1] - jbeg;
    const bool fits = (cnt <= SORT_CAP);   // sort perf-only; isd always written
    if (tid < NPB) hist[tid] = 0;
    __syncthreads();
    for (int k = tid; k < cnt; k += 512) {
        uint32_t p = buf[jbeg + k];
        if (fits) stage[k] = p;
        atomicAdd(&hist[(p >> 16) & (NPB - 1)], 1);
    }
    __syncthreads();   // drains global reads before in-place overwrite
    if (tid < NPB) {   // wave 0: 64-wide exclusive scan via shfl + isd write
        int h = hist[tid];
        int x = h;
#pragma unroll
        for (int d = 1; d < 64; d <<= 1) {
            int t = __shfl_up(x, d);
            if (tid >= d) x += t;
        }
        cur[tid] = x - h;
        int node = (bb << NPB_LOG2) + tid;
        if (node < n_rows) isd[node] = h > 0 ? rsqrtf((float)h) : 0.f;
    }
    __syncthreads();
    if (fits) {
        for (int k = tid; k < cnt; k += 512) {
            uint32_t p = stage[k];
            int slot = atomicAdd(&cur[(p >> 16) & (NPB - 1)], 1);
            buf[jbeg + slot] = p;
        }
    }
}

// Wave per CSCAN_CH consecutive dst-sorted edges; register accumulate,
// flush on dst change via native f32 atomic. (Proven 58.6us/dir — the
// fetch floor of this decomposition; r8/r9/r10 restructures all lost.)
__global__ __launch_bounds__(256) void cscan_kernel(
        const ushort* __restrict__ xb, const uint32_t* __restrict__ packed, int E,
        const float* __restrict__ isd, float* __restrict__ out) {
    const int lane = threadIdx.x & 63;
    const int wave = (blockIdx.x << 2) + (threadIdx.x >> 6);
    const int base = wave * CSCAN_CH;
    if (base >= E) return;
    const int n = min(CSCAN_CH, E - base);
    const uint32_t* pp = packed + base;
    float ax = 0.f, ay = 0.f;
    int cur = (int)(pp[0] >> 16);

#define ROW(pv) (*reinterpret_cast<const uint32_t*>( \
        xb + (((size_t)((pv) & 0xffffu)) << 7) + (lane << 1)))
#define UPX(rv) __uint_as_float((rv) << 16)
#define UPY(rv) __uint_as_float((rv) & 0xffff0000u)
#define FLUSH() do { float w_ = isd[cur];                                  \
        unsafeAtomicAdd(out + ((size_t)cur << 7) + lane, ax * w_);         \
        unsafeAtomicAdd(out + ((size_t)cur << 7) + 64 + lane, ay * w_);    \
        ax = 0.f; ay = 0.f; } while (0)
#define PROC(pv, rv) do { int d_ = (int)((pv) >> 16);                      \
        if (d_ != cur) { FLUSH(); cur = d_; }                              \
        ax += UPX(rv); ay += UPY(rv); } while (0)
#define GRP8(Aa, Ab, r0, r1, r2, r3, r4, r5, r6, r7) do {                  \
    if ((((Aa.x ^ Ab.w) >> 16) == 0) && ((int)(Aa.x >> 16) == cur)) {      \
        float sx = ((UPX(r0) + UPX(r1)) + (UPX(r2) + UPX(r3)))             \
                 + ((UPX(r4) + UPX(r5)) + (UPX(r6) + UPX(r7)));            \
        float sy = ((UPY(r0) + UPY(r1)) + (UPY(r2) + UPY(r3)))             \
                 + ((UPY(r4) + UPY(r5)) + (UPY(r6) + UPY(r7)));            \
        ax += sx; ay += sy;                                                \
    } else {                                                               \
        PROC(Aa.x, r0); PROC(Aa.y, r1); PROC(Aa.z, r2); PROC(Aa.w, r3);    \
        PROC(Ab.x, r4); PROC(Ab.y, r5); PROC(Ab.z, r6); PROC(Ab.w, r7);    \
    } } while (0)

    int k = 0;
    if (n >= 24) {
        uint4 P0a = *(const uint4*)(pp + 0),  P0b = *(const uint4*)(pp + 4);
        uint4 P1a = *(const uint4*)(pp + 8),  P1b = *(const uint4*)(pp + 12);
        uint32_t a0 = ROW(P0a.x), a1 = ROW(P0a.y), a2 = ROW(P0a.z), a3 = ROW(P0a.w),
                 a4 = ROW(P0b.x), a5 = ROW(P0b.y), a6 = ROW(P0b.z), a7 = ROW(P0b.w);
        uint4 P2a = *(const uint4*)(pp + 16), P2b = *(const uint4*)(pp + 20);
        uint32_t b0 = ROW(P1a.x), b1 = ROW(P1a.y), b2 = ROW(P1a.z), b3 = ROW(P1a.w),
                 b4 = ROW(P1b.x), b5 = ROW(P1b.y), b6 = ROW(P1b.z), b7 = ROW(P1b.w);
        for (k = 24; k + 8 <= n; k += 8) {
            uint4 P3a = *(const uint4*)(pp + k), P3b = *(const uint4*)(pp + k + 4);
            uint32_t c0 = ROW(P2a.x), c1 = ROW(P2a.y), c2 = ROW(P2a.z), c3 = ROW(P2a.w),
                     c4 = ROW(P2b.x), c5 = ROW(P2b.y), c6 = ROW(P2b.z), c7 = ROW(P2b.w);
            GRP8(P0a, P0b, a0, a1, a2, a3, a4, a5, a6, a7);
            P0a = P1a; P0b = P1b; P1a = P2a; P1b = P2b; P2a = P3a; P2b = P3b;
            a0 = b0; a1 = b1; a2 = b2; a3 = b3; a4 = b4; a5 = b5; a6 = b6; a7 = b7;
            b0 = c0; b1 = c1; b2 = c2; b3 = c3; b4 = c4; b5 = c5; b6 = c6; b7 = c7;
        }
        uint32_t c0 = ROW(P2a.x), c1 = ROW(P2a.y), c2 = ROW(P2a.z), c3 = ROW(P2a.w),
                 c4 = ROW(P2b.x), c5 = ROW(P2b.y), c6 = ROW(P2b.z), c7 = ROW(P2b.w);
        GRP8(P0a, P0b, a0, a1, a2, a3, a4, a5, a6, a7);
        GRP8(P1a, P1b, b0, b1, b2, b3, b4, b5, b6, b7);
        GRP8(P2a, P2b, c0, c1, c2, c3, c4, c5, c6, c7);
    }
    for (; k < n; ++k) {
        uint32_t p = pp[k];
        uint32_t r = ROW(p);
        PROC(p, r);
    }
    FLUSH();
#undef GRP8
#undef PROC
#undef FLUSH
#undef UPY
#undef UPX
#undef ROW
}

// ---- minimal-ws fallback ---------------------------------------------------

__global__ void deg_kernel(const int* __restrict__ u, const int* __restrict__ s,
                           int E, int* __restrict__ udeg, int* __restrict__ sdeg) {
    int i = blockIdx.x * blockDim.x + threadIdx.x;
    if (i < E) {
        atomicAdd(&udeg[u[i]], 1);
        atomicAdd(&sdeg[s[i]], 1);
    }
}

__global__ void init_isd_kernel(const int* __restrict__ udeg, const int* __restrict__ sdeg,
                                float* __restrict__ isd_u, float* __restrict__ isd_s,
                                int n_user, int m_spot) {
    int i = blockIdx.x * blockDim.x + threadIdx.x;
    if (i < n_user) { int d = udeg[i]; isd_u[i] = d > 0 ? rsqrtf((float)d) : 0.f; }
    if (i < m_spot) { int d = sdeg[i]; isd_s[i] = d > 0 ? rsqrtf((float)d) : 0.f; }
}

__global__ __launch_bounds__(256) void scatter_kernel(const float* __restrict__ spot_x,
                                                      const float* __restrict__ user_x,
                                                      const int* __restrict__ u,
                                                      const int* __restrict__ s, int E,
                                                      const float* __restrict__ isd_u,
                                                      const float* __restrict__ isd_s,
                                                      float* __restrict__ spot_out,
                                                      float* __restrict__ user_out) {
    const int lane = threadIdx.x & 63;
    const int e = blockIdx.x * 4 + (threadIdx.x >> 6);
    if (e >= E) return;
    const int uu = u[e], ss = s[e];
    const float w = isd_u[uu] * isd_s[ss];
    const float2 sv = *reinterpret_cast<const float2*>(spot_x + (size_t)ss * 128 + lane * 2);
    const float2 uv = *reinterpret_cast<const float2*>(user_x + (size_t)uu * 128 + lane * 2);
    atomicAdd(&user_out[(size_t)uu * 128 + lane * 2 + 0], sv.x * w);
    atomicAdd(&user_out[(size_t)uu * 128 + lane * 2 + 1], sv.y * w);
    atomicAdd(&spot_out[(size_t)ss * 128 + lane * 2 + 0], uv.x * w);
    atomicAdd(&spot_out[(size_t)ss * 128 + lane * 2 + 1], uv.y * w);
}

static inline char* align256(char* p) {
    return (char*)(((uintptr_t)p + 255u) & ~(uintptr_t)255u);
}

extern "C" void kernel_launch(void* const* d_in, const int* in_sizes, int n_in,
                              void* d_out, int out_size, void* d_ws, size_t ws_size,
                              hipStream_t stream) {
    const float* spot_x = (const float*)d_in[0];
    const float* user_x = (const float*)d_in[1];
    const int*   edges  = (const int*)d_in[2];
    const int M = in_sizes[0] / 128;   // spots
    const int N = in_sizes[1] / 128;   // users
    const int E = in_sizes[2] / 2;
    const int* u = edges;        // user_spot[0]
    const int* s = edges + E;    // user_spot[1]
    float* spot_out = (float*)d_out;
    float* user_out = (float*)d_out + (size_t)M * 128;

    const int nbu = (N + NPB - 1) / NPB;
    const int nbs = (M + NPB - 1) / NPB;
    const int nm = (N > M) ? N : M;
    const int gpart = (E + PART_CHUNK - 1) / PART_CHUNK;
    const int gscan = ((E + CSCAN_CH - 1) / CSCAN_CH + 3) / 4;

    // Common metadata layout (shared by tiers A and B).
    char* ws = (char*)d_ws;
    float*    isd_u = (float*)ws; ws = align256(ws + sizeof(float) * (size_t)N);
    float*    isd_s = (float*)ws; ws = align256(ws + sizeof(float) * (size_t)M);
    int*      bd    = (int*)ws;   ws = align256(ws + sizeof(int) * (size_t)(nbu + nbs));
    int*      buoff = (int*)ws;   ws = align256(ws + sizeof(int) * (size_t)(nbu + 1));
    int*      bsoff = (int*)ws;   ws = align256(ws + sizeof(int) * (size_t)(nbs + 1));
    int*      gcu   = (int*)ws;   ws = align256(ws + sizeof(int) * (size_t)nbu);
    int*      gcs   = (int*)ws;   ws = align256(ws + sizeof(int) * (size_t)nbs);
    uint32_t* bufU  = (uint32_t*)ws; ws = align256(ws + sizeof(uint32_t) * (size_t)E);
    uint32_t* bufS  = (uint32_t*)ws; ws = align256(ws + sizeof(uint32_t) * (size_t)E);
    ushort*   xbs   = (ushort*)ws;   // tier A: spot table (tier B: union slot)
    ushort*   xbu   = (ushort*)align256((char*)xbs + sizeof(ushort) * ((size_t)M * 128));
    size_t tierA_needed = (size_t)((char*)xbu - (char*)d_ws)
                        + sizeof(ushort) * ((size_t)N * 128);
    size_t tierB_needed = (size_t)((char*)xbs - (char*)d_ws)
                        + sizeof(ushort) * ((size_t)nm * 128);

    if (tierB_needed <= ws_size && nbu <= MAXB && nbs <= MAXB) {
        hipMemsetAsync(bd, 0, sizeof(int) * (size_t)(nbu + nbs), stream);
        hipMemsetAsync(d_out, 0, sizeof(float) * (size_t)out_size, stream);
        bhist_kernel<<<(E + BH_CHUNK - 1) / BH_CHUNK, 256, 0, stream>>>(
            u, s, E, nbu, nbs, bd);
        scan2_kernel<<<2, 1024, 0, stream>>>(bd, nbu, nbs, buoff, bsoff, gcu, gcs);
        part2_kernel<<<gpart, 256, 0, stream>>>(u, s, E, nbu, nbs, gcu, gcs, bufU, bufS);
        bsort3b_kernel<<<nbu + nbs, 512, 0, stream>>>(
            bufU, bufS, buoff, bsoff, nbu, isd_u, isd_s, N, M);
        if (tierA_needed <= ws_size) {
            // ---- tier A: both tables resident, sequential cscans ---------
            convert2_kernel<<<(((M + N) << 6) + 255) / 256, 256, 0, stream>>>(
                spot_x, user_x, isd_s, isd_u, xbs, xbu, M, N);
            cscan_kernel<<<gscan, 256, 0, stream>>>(xbs, bufU, E, isd_u, user_out);
            cscan_kernel<<<gscan, 256, 0, stream>>>(xbu, bufS, E, isd_s, spot_out);
        } else {
            // ---- tier B: union table slot, sequential --------------------
            ushort* xb = xbs;
            convert_kernel<<<((M << 6) + 255) / 256, 256, 0, stream>>>(spot_x, isd_s, xb, M);
            cscan_kernel<<<gscan, 256, 0, stream>>>(xb, bufU, E, isd_u, user_out);
            convert_kernel<<<((N << 6) + 255) / 256, 256, 0, stream>>>(user_x, isd_u, xb, N);
            cscan_kernel<<<gscan, 256, 0, stream>>>(xb, bufS, E, isd_s, spot_out);
        }
        return;
    }

    // ---- minimal-ws fallback: degree + atomic scatter ----------------------
    {
        char* w2 = (char*)d_ws;
        int*   udeg2  = (int*)w2;   w2 += sizeof(int) * (size_t)N;
        int*   sdeg2  = (int*)w2;   w2 += sizeof(int) * (size_t)M;
        float* isd_u2 = (float*)w2; w2 += sizeof(float) * (size_t)N;
        float* isd_s2 = (float*)w2; w2 += sizeof(float) * (size_t)M;
        if ((size_t)(w2 - (char*)d_ws) <= ws_size) {
            hipMemsetAsync(udeg2, 0, sizeof(int) * (size_t)(N + M), stream);
            deg_kernel<<<(E + 255) / 256, 256, 0, stream>>>(u, s, E, udeg2, sdeg2);
            init_isd_kernel<<<(nm + 255) / 256, 256, 0, stream>>>(
                udeg2, sdeg2, isd_u2, isd_s2, N, M);
            hipMemsetAsync(d_out, 0, sizeof(float) * (size_t)out_size, stream);
            scatter_kernel<<<((size_t)E + 3) / 4, 256, 0, stream>>>(
                spot_x, user_x, u, s, E, isd_u2, isd_s2, spot_out, user_out);
        }
    }
}

// Round 15
// 235.189 us; speedup vs baseline: 1.2258x; 1.0040x over previous
//
#include <hip/hip_runtime.h>
#include <stdint.h>

// ---------------------------------------------------------------------------
// UserSpotConv: bipartite GCN aggregation.
//   user_out[u] = isd_u[u] * sum_{e: u_e=u} spot_x[s_e] * isd_s[s_e]
//   spot_out[s] = isd_s[s] * sum_{e: s_e=s} user_x[u_e] * isd_u[u_e]
// Round 15: part2 is latency-bound (VALUBusy 4.3%, 12 waves/CU). Keep r11's
// proven structure VERBATIM (r13's algorithmic rewrite regressed); change
// only launch shape: 512 threads/block (loops stride 512) + MAXB 768->704
// (LDS 41.5->38.0 KB) -> 4 blocks/CU x 8 waves = 32 waves/CU (was 12).
// cscan untouched (58.6 us/dir = established fetch floor).
// ---------------------------------------------------------------------------

#define NPB_LOG2 6
#define NPB 64             // destination nodes per bucket
#define MAXB 704           // max buckets per direction (nbs=670, nbu=424)
#define PART_CHUNK 2048    // edges per block in part2_kernel
#define BH_CHUNK 16384     // edges per block in bhist_kernel
#define SORT_CAP 8192      // max edges per bucket for bsort staging
#define CSCAN_CH 256       // edges per wave in cscan

__device__ __forceinline__ ushort f2bf(float f) {
    uint32_t u = __float_as_uint(f);
    return (ushort)((u + 0x7fffu + ((u >> 16) & 1u)) >> 16);  // RNE
}

// Bucket-level histogram for BOTH directions in one pass.
__global__ __launch_bounds__(256) void bhist_kernel(
        const int* __restrict__ u, const int* __restrict__ s, int E,
        int nbu, int nbs, int* __restrict__ bd) {
    __shared__ int hist[2 * MAXB];
    const int tid = threadIdx.x;
    const int nb = nbu + nbs;
    const int beg = blockIdx.x * BH_CHUNK;
    const int end = min(beg + BH_CHUNK, E);
    for (int b = tid; b < nb; b += 256) hist[b] = 0;
    __syncthreads();
    for (int i = beg + tid; i < end; i += 256) {
        atomicAdd(&hist[u[i] >> NPB_LOG2], 1);
        atomicAdd(&hist[nbu + (s[i] >> NPB_LOG2)], 1);
    }
    __syncthreads();
    for (int b = tid; b < nb; b += 256) {
        int h = hist[b];
        if (h) atomicAdd(&bd[b], h);
    }
}

// Fused dual exclusive scan (block 0: u-buckets, block 1: s-buckets) that
// also initializes the part2 global cursors. n <= 1024 (MAXB=704).
__global__ __launch_bounds__(1024) void scan2_kernel(
        const int* __restrict__ bd, int nbu, int nbs,
        int* __restrict__ buoff, int* __restrict__ bsoff,
        int* __restrict__ gcu, int* __restrict__ gcs) {
    __shared__ int wsums[16];
    __shared__ int total;
    const int tid = threadIdx.x, lane = tid & 63, wid = tid >> 6;
    const int n   = blockIdx.x ? nbs : nbu;
    const int* in = blockIdx.x ? (bd + nbu) : bd;
    int* out = blockIdx.x ? bsoff : buoff;
    int* gc  = blockIdx.x ? gcs   : gcu;
    int v = (tid < n) ? in[tid] : 0;
    int x = v;
#pragma unroll
    for (int d = 1; d < 64; d <<= 1) {
        int t = __shfl_up(x, d);
        if (lane >= d) x += t;
    }
    if (lane == 63) wsums[wid] = x;
    __syncthreads();
    if (tid == 0) {
        int run = 0;
#pragma unroll
        for (int w = 0; w < 16; ++w) { int t = wsums[w]; wsums[w] = run; run += t; }
        total = run;
    }
    __syncthreads();
    int excl = wsums[wid] + (x - v);
    if (tid < n) { out[tid] = excl; gc[tid] = excl; }
    if (tid == 0) out[n] = total;
}

// xb row layout is PERMUTED: slot 2c holds col c, slot 2c+1 holds col c+64,
// so a lane's uint32 load at byte row*256+4*l yields cols (l, l+64).
// convert2: both tables in one dispatch.
__global__ void convert2_kernel(const float* __restrict__ spot_x,
                                const float* __restrict__ user_x,
                                const float* __restrict__ isd_s,
                                const float* __restrict__ isd_u,
                                ushort* __restrict__ xbs, ushort* __restrict__ xbu,
                                int M, int N) {
    int idx = blockIdx.x * blockDim.x + threadIdx.x;
    if (idx >= ((M + N) << 6)) return;
    int row = idx >> 6, c = idx & 63;
    const float* x; float w; ushort* xb;
    if (row < M) { x = spot_x + ((size_t)row << 7); w = isd_s[row]; xb = xbs + ((size_t)row << 7); }
    else { row -= M; x = user_x + ((size_t)row << 7); w = isd_u[row]; xb = xbu + ((size_t)row << 7); }
    ushort2 o;
    o.x = f2bf(x[c] * w);
    o.y = f2bf(x[c + 64] * w);
    *reinterpret_cast<ushort2*>(xb + 2 * c) = o;
}

// Single-table convert (tier B).
__global__ void convert_kernel(const float* __restrict__ x, const float* __restrict__ isd,
                               ushort* __restrict__ xb, int n_rows) {
    int idx = blockIdx.x * blockDim.x + threadIdx.x;
    if (idx >= (n_rows << 6)) return;
    int row = idx >> 6, c = idx & 63;
    float w = isd[row];
    const float* xr = x + ((size_t)row << 7);
    ushort2 o;
    o.x = f2bf(xr[c] * w);
    o.y = f2bf(xr[c + 64] * w);
    *reinterpret_cast<ushort2*>(xb + ((size_t)row << 7) + 2 * c) = o;
}

// Both-direction partition in ONE kernel (r11-proven structure, 512 threads):
// reads each edge once, stages both (u<<16|s) and (s<<16|u) into LDS
// bucket-ordered, element-parallel coalesced run flush.
__global__ __launch_bounds__(512) void part2_kernel(
        const int* __restrict__ u, const int* __restrict__ s, int E,
        int nbu, int nbs, int* __restrict__ gcu, int* __restrict__ gcs,
        uint32_t* __restrict__ outU, uint32_t* __restrict__ outS) {
    __shared__ int histU[MAXB], loffU[MAXB], gbaseU[MAXB], curU[MAXB];
    __shared__ int histS[MAXB], loffS[MAXB], gbaseS[MAXB], curS[MAXB];
    __shared__ int wsum[8];
    __shared__ uint32_t sbufU[PART_CHUNK];
    __shared__ uint32_t sbufS[PART_CHUNK];
    const int tid = threadIdx.x;
    const int lane = tid & 63;
    const int wid = tid >> 6;
    const int beg = blockIdx.x * PART_CHUNK;
    const int end = min(beg + PART_CHUNK, E);
    const int cnt_total = end - beg;
    for (int b = tid; b < nbu; b += 512) histU[b] = 0;
    for (int b = tid; b < nbs; b += 512) histS[b] = 0;
    __syncthreads();
    for (int i = beg + tid; i < end; i += 512) {
        atomicAdd(&histU[u[i] >> NPB_LOG2], 1);
        atomicAdd(&histS[s[i] >> NPB_LOG2], 1);
    }
    __syncthreads();
    // per dir: exclusive scan of hist into loff (2 buckets per thread)
    for (int dir = 0; dir < 2; ++dir) {
        int nb = dir ? nbs : nbu;
        int* hist = dir ? histS : histU;
        int* loff = dir ? loffS : loffU;
        int b0 = tid * 2;
        int h0 = (b0 + 0 < nb) ? hist[b0 + 0] : 0;
        int h1 = (b0 + 1 < nb) ? hist[b0 + 1] : 0;
        int tsum = h0 + h1;
        int x = tsum;
#pragma unroll
        for (int d = 1; d < 64; d <<= 1) {
            int t = __shfl_up(x, d);
            if (lane >= d) x += t;
        }
        if (lane == 63) wsum[wid] = x;
        __syncthreads();
        if (tid == 0) {
            int run = 0;
#pragma unroll
            for (int w = 0; w < 8; ++w) { int t = wsum[w]; wsum[w] = run; run += t; }
        }
        __syncthreads();
        int base = wsum[wid] + (x - tsum);
        if (b0 + 0 < nb) loff[b0 + 0] = base;
        if (b0 + 1 < nb) loff[b0 + 1] = base + h0;
        __syncthreads();
    }
    for (int b = tid; b < nbu; b += 512) {
        curU[b] = loffU[b];
        int c = histU[b];
        gbaseU[b] = c > 0 ? atomicAdd(&gcu[b], c) : 0;
    }
    for (int b = tid; b < nbs; b += 512) {
        curS[b] = loffS[b];
        int c = histS[b];
        gbaseS[b] = c > 0 ? atomicAdd(&gcs[b], c) : 0;
    }
    __syncthreads();
    for (int i = beg + tid; i < end; i += 512) {
        int uu = u[i], ss = s[i];
        int lu = atomicAdd(&curU[uu >> NPB_LOG2], 1);
        sbufU[lu] = ((uint32_t)uu << 16) | (uint32_t)ss;
        int ls = atomicAdd(&curS[ss >> NPB_LOG2], 1);
        sbufS[ls] = ((uint32_t)ss << 16) | (uint32_t)uu;
    }
    __syncthreads();
    for (int k = tid; k < cnt_total; k += 512) {
        uint32_t p = sbufU[k];
        int b = (int)(p >> (16 + NPB_LOG2));
        outU[gbaseU[b] + (k - loffU[b])] = p;
        uint32_t q = sbufS[k];
        int b2 = (int)(q >> (16 + NPB_LOG2));
        outS[gbaseS[b2] + (k - loffS[b2])] = q;
    }
}

// Combined-direction per-bucket counting sort by dst, in place (LDS-staged),
// AND write isd = rsqrt(degree). 512 threads (8 waves) for latency hiding.
__global__ __launch_bounds__(512) void bsort3b_kernel(
        uint32_t* __restrict__ bufU, uint32_t* __restrict__ bufS,
        const int* __restrict__ buoff, const int* __restrict__ bsoff, int nbu,
        float* __restrict__ isd_u, float* __restrict__ isd_s, int N, int M) {
    __shared__ uint32_t stage[SORT_CAP];
    __shared__ int hist[NPB];
    __shared__ int cur[NPB];
    const int tid = threadIdx.x;
    const int b = blockIdx.x;
    uint32_t* buf; const int* boff; float* isd; int n_rows; int bb;
    if (b < nbu) { buf = bufU; boff = buoff; isd = isd_u; n_rows = N; bb = b; }
    else         { buf = bufS; boff = bsoff; isd = isd_s; n_rows = M; bb = b - nbu; }
    const int jbeg = boff[bb];
    const int cnt = boff[bb + 1] - jbeg;
    const bool fits = (cnt <= SORT_CAP);   // sort perf-only; isd always written
    if (tid < NPB) hist[tid] = 0;
    __syncthreads();
    for (int k = tid; k < cnt; k += 512) {
        uint32_t p = buf[jbeg + k];
        if (fits) stage[k] = p;
        atomicAdd(&hist[(p >> 16) & (NPB - 1)], 1);
    }
    __syncthreads();   // drains global reads before in-place overwrite
    if (tid < NPB) {   // wave 0: 64-wide exclusive scan via shfl + isd write
        int h = hist[tid];
        int x = h;
#pragma unroll
        for (int d = 1; d < 64; d <<= 1) {
            int t = __shfl_up(x, d);
            if (tid >= d) x += t;
        }
        cur[tid] = x - h;
        int node = (bb << NPB_LOG2) + tid;
        if (node < n_rows) isd[node] = h > 0 ? rsqrtf((float)h) : 0.f;
    }
    __syncthreads();
    if (fits) {
        for (int k = tid; k < cnt; k += 512) {
            uint32_t p = stage[k];
            int slot = atomicAdd(&cur[(p >> 16) & (NPB - 1)], 1);
            buf[jbeg + slot] = p;
        }
    }
}

// Wave per CSCAN_CH consecutive dst-sorted edges; register accumulate,
// flush on dst change via native f32 atomic. (Proven 58.6us/dir — the
// fetch floor of this decomposition; r8/r9/r10 restructures all lost.)
__global__ __launch_bounds__(256) void cscan_kernel(
        const ushort* __restrict__ xb, const uint32_t* __restrict__ packed, int E,
        const float* __restrict__ isd, float* __restrict__ out) {
    const int lane = threadIdx.x & 63;
    const int wave = (blockIdx.x << 2) + (threadIdx.x >> 6);
    const int base = wave * CSCAN_CH;
    if (base >= E) return;
    const int n = min(CSCAN_CH, E - base);
    const uint32_t* pp = packed + base;
    float ax = 0.f, ay = 0.f;
    int cur = (int)(pp[0] >> 16);

#define ROW(pv) (*reinterpret_cast<const uint32_t*>( \
        xb + (((size_t)((pv) & 0xffffu)) << 7) + (lane << 1)))
#define UPX(rv) __uint_as_float((rv) << 16)
#define UPY(rv) __uint_as_float((rv) & 0xffff0000u)
#define FLUSH() do { float w_ = isd[cur];                                  \
        unsafeAtomicAdd(out + ((size_t)cur << 7) + lane, ax * w_);         \
        unsafeAtomicAdd(out + ((size_t)cur << 7) + 64 + lane, ay * w_);    \
        ax = 0.f; ay = 0.f; } while (0)
#define PROC(pv, rv) do { int d_ = (int)((pv) >> 16);                      \
        if (d_ != cur) { FLUSH(); cur = d_; }                              \
        ax += UPX(rv); ay += UPY(rv); } while (0)
#define GRP8(Aa, Ab, r0, r1, r2, r3, r4, r5, r6, r7) do {                  \
    if ((((Aa.x ^ Ab.w) >> 16) == 0) && ((int)(Aa.x >> 16) == cur)) {      \
        float sx = ((UPX(r0) + UPX(r1)) + (UPX(r2) + UPX(r3)))             \
                 + ((UPX(r4) + UPX(r5)) + (UPX(r6) + UPX(r7)));            \
        float sy = ((UPY(r0) + UPY(r1)) + (UPY(r2) + UPY(r3)))             \
                 + ((UPY(r4) + UPY(r5)) + (UPY(r6) + UPY(r7)));            \
        ax += sx; ay += sy;                                                \
    } else {                                                               \
        PROC(Aa.x, r0); PROC(Aa.y, r1); PROC(Aa.z, r2); PROC(Aa.w, r3);    \
        PROC(Ab.x, r4); PROC(Ab.y, r5); PROC(Ab.z, r6); PROC(Ab.w, r7);    \
    } } while (0)

    int k = 0;
    if (n >= 24) {
        uint4 P0a = *(const uint4*)(pp + 0),  P0b = *(const uint4*)(pp + 4);
        uint4 P1a = *(const uint4*)(pp + 8),  P1b = *(const uint4*)(pp + 12);
        uint32_t a0 = ROW(P0a.x), a1 = ROW(P0a.y), a2 = ROW(P0a.z), a3 = ROW(P0a.w),
                 a4 = ROW(P0b.x), a5 = ROW(P0b.y), a6 = ROW(P0b.z), a7 = ROW(P0b.w);
        uint4 P2a = *(const uint4*)(pp + 16), P2b = *(const uint4*)(pp + 20);
        uint32_t b0 = ROW(P1a.x), b1 = ROW(P1a.y), b2 = ROW(P1a.z), b3 = ROW(P1a.w),
                 b4 = ROW(P1b.x), b5 = ROW(P1b.y), b6 = ROW(P1b.z), b7 = ROW(P1b.w);
        for (k = 24; k + 8 <= n; k += 8) {
            uint4 P3a = *(const uint4*)(pp + k), P3b = *(const uint4*)(pp + k + 4);
            uint32_t c0 = ROW(P2a.x), c1 = ROW(P2a.y), c2 = ROW(P2a.z), c3 = ROW(P2a.w),
                     c4 = ROW(P2b.x), c5 = ROW(P2b.y), c6 = ROW(P2b.z), c7 = ROW(P2b.w);
            GRP8(P0a, P0b, a0, a1, a2, a3, a4, a5, a6, a7);
            P0a = P1a; P0b = P1b; P1a = P2a; P1b = P2b; P2a = P3a; P2b = P3b;
            a0 = b0; a1 = b1; a2 = b2; a3 = b3; a4 = b4; a5 = b5; a6 = b6; a7 = b7;
            b0 = c0; b1 = c1; b2 = c2; b3 = c3; b4 = c4; b5 = c5; b6 = c6; b7 = c7;
        }
        uint32_t c0 = ROW(P2a.x), c1 = ROW(P2a.y), c2 = ROW(P2a.z), c3 = ROW(P2a.w),
                 c4 = ROW(P2b.x), c5 = ROW(P2b.y), c6 = ROW(P2b.z), c7 = ROW(P2b.w);
        GRP8(P0a, P0b, a0, a1, a2, a3, a4, a5, a6, a7);
        GRP8(P1a, P1b, b0, b1, b2, b3, b4, b5, b6, b7);
        GRP8(P2a, P2b, c0, c1, c2, c3, c4, c5, c6, c7);
    }
    for (; k < n; ++k) {
        uint32_t p = pp[k];
        uint32_t r = ROW(p);
        PROC(p, r);
    }
    FLUSH();
#undef GRP8
#undef PROC
#undef FLUSH
#undef UPY
#undef UPX
#undef ROW
}

// ---- minimal-ws fallback ---------------------------------------------------

__global__ void deg_kernel(const int* __restrict__ u, const int* __restrict__ s,
                           int E, int* __restrict__ udeg, int* __restrict__ sdeg) {
    int i = blockIdx.x * blockDim.x + threadIdx.x;
    if (i < E) {
        atomicAdd(&udeg[u[i]], 1);
        atomicAdd(&sdeg[s[i]], 1);
    }
}

__global__ void init_isd_kernel(const int* __restrict__ udeg, const int* __restrict__ sdeg,
                                float* __restrict__ isd_u, float* __restrict__ isd_s,
                                int n_user, int m_spot) {
    int i = blockIdx.x * blockDim.x + threadIdx.x;
    if (i < n_user) { int d = udeg[i]; isd_u[i] = d > 0 ? rsqrtf((float)d) : 0.f; }
    if (i < m_spot) { int d = sdeg[i]; isd_s[i] = d > 0 ? rsqrtf((float)d) : 0.f; }
}

__global__ __launch_bounds__(256) void scatter_kernel(const float* __restrict__ spot_x,
                                                      const float* __restrict__ user_x,
                                                      const int* __restrict__ u,
                                                      const int* __restrict__ s, int E,
                                                      const float* __restrict__ isd_u,
                                                      const float* __restrict__ isd_s,
                                                      float* __restrict__ spot_out,
                                                      float* __restrict__ user_out) {
    const int lane = threadIdx.x & 63;
    const int e = blockIdx.x * 4 + (threadIdx.x >> 6);
    if (e >= E) return;
    const int uu = u[e], ss = s[e];
    const float w = isd_u[uu] * isd_s[ss];
    const float2 sv = *reinterpret_cast<const float2*>(spot_x + (size_t)ss * 128 + lane * 2);
    const float2 uv = *reinterpret_cast<const float2*>(user_x + (size_t)uu * 128 + lane * 2);
    atomicAdd(&user_out[(size_t)uu * 128 + lane * 2 + 0], sv.x * w);
    atomicAdd(&user_out[(size_t)uu * 128 + lane * 2 + 1], sv.y * w);
    atomicAdd(&spot_out[(size_t)ss * 128 + lane * 2 + 0], uv.x * w);
    atomicAdd(&spot_out[(size_t)ss * 128 + lane * 2 + 1], uv.y * w);
}

static inline char* align256(char* p) {
    return (char*)(((uintptr_t)p + 255u) & ~(uintptr_t)255u);
}

extern "C" void kernel_launch(void* const* d_in, const int* in_sizes, int n_in,
                              void* d_out, int out_size, void* d_ws, size_t ws_size,
                              hipStream_t stream) {
    const float* spot_x = (const float*)d_in[0];
    const float* user_x = (const float*)d_in[1];
    const int*   edges  = (const int*)d_in[2];
    const int M = in_sizes[0] / 128;   // spots
    const int N = in_sizes[1] / 128;   // users
    const int E = in_sizes[2] / 2;
    const int* u = edges;        // user_spot[0]
    const int* s = edges + E;    // user_spot[1]
    float* spot_out = (float*)d_out;
    float* user_out = (float*)d_out + (size_t)M * 128;

    const int nbu = (N + NPB - 1) / NPB;
    const int nbs = (M + NPB - 1) / NPB;
    const int nm = (N > M) ? N : M;
    const int gpart = (E + PART_CHUNK - 1) / PART_CHUNK;
    const int gscan = ((E + CSCAN_CH - 1) / CSCAN_CH + 3) / 4;

    // Common metadata layout (shared by tiers A and B).
    char* ws = (char*)d_ws;
    float*    isd_u = (float*)ws; ws = align256(ws + sizeof(float) * (size_t)N);
    float*    isd_s = (float*)ws; ws = align256(ws + sizeof(float) * (size_t)M);
    int*      bd    = (int*)ws;   ws = align256(ws + sizeof(int) * (size_t)(nbu + nbs));
    int*      buoff = (int*)ws;   ws = align256(ws + sizeof(int) * (size_t)(nbu + 1));
    int*      bsoff = (int*)ws;   ws = align256(ws + sizeof(int) * (size_t)(nbs + 1));
    int*      gcu   = (int*)ws;   ws = align256(ws + sizeof(int) * (size_t)nbu);
    int*      gcs   = (int*)ws;   ws = align256(ws + sizeof(int) * (size_t)nbs);
    uint32_t* bufU  = (uint32_t*)ws; ws = align256(ws + sizeof(uint32_t) * (size_t)E);
    uint32_t* bufS  = (uint32_t*)ws; ws = align256(ws + sizeof(uint32_t) * (size_t)E);
    ushort*   xbs   = (ushort*)ws;   // tier A: spot table (tier B: union slot)
    ushort*   xbu   = (ushort*)align256((char*)xbs + sizeof(ushort) * ((size_t)M * 128));
    size_t tierA_needed = (size_t)((char*)xbu - (char*)d_ws)
                        + sizeof(ushort) * ((size_t)N * 128);
    size_t tierB_needed = (size_t)((char*)xbs - (char*)d_ws)
                        + sizeof(ushort) * ((size_t)nm * 128);

    if (tierB_needed <= ws_size && nbu <= MAXB && nbs <= MAXB) {
        hipMemsetAsync(bd, 0, sizeof(int) * (size_t)(nbu + nbs), stream);
        hipMemsetAsync(d_out, 0, sizeof(float) * (size_t)out_size, stream);
        bhist_kernel<<<(E + BH_CHUNK - 1) / BH_CHUNK, 256, 0, stream>>>(
            u, s, E, nbu, nbs, bd);
        scan2_kernel<<<2, 1024, 0, stream>>>(bd, nbu, nbs, buoff, bsoff, gcu, gcs);
        part2_kernel<<<gpart, 512, 0, stream>>>(u, s, E, nbu, nbs, gcu, gcs, bufU, bufS);
        bsort3b_kernel<<<nbu + nbs, 512, 0, stream>>>(
            bufU, bufS, buoff, bsoff, nbu, isd_u, isd_s, N, M);
        if (tierA_needed <= ws_size) {
            // ---- tier A: both tables resident, sequential cscans ---------
            convert2_kernel<<<(((M + N) << 6) + 255) / 256, 256, 0, stream>>>(
                spot_x, user_x, isd_s, isd_u, xbs, xbu, M, N);
            cscan_kernel<<<gscan, 256, 0, stream>>>(xbs, bufU, E, isd_u, user_out);
            cscan_kernel<<<gscan, 256, 0, stream>>>(xbu, bufS, E, isd_s, spot_out);
        } else {
            // ---- tier B: union table slot, sequential --------------------
            ushort* xb = xbs;
            convert_kernel<<<((M << 6) + 255) / 256, 256, 0, stream>>>(spot_x, isd_s, xb, M);
            cscan_kernel<<<gscan, 256, 0, stream>>>(xb, bufU, E, isd_u, user_out);
            convert_kernel<<<((N << 6) + 255) / 256, 256, 0, stream>>>(user_x, isd_u, xb, N);
            cscan_kernel<<<gscan, 256, 0, stream>>>(xb, bufS, E, isd_s, spot_out);
        }
        return;
    }

    // ---- minimal-ws fallback: degree + atomic scatter ----------------------
    {
        char* w2 = (char*)d_ws;
        int*   udeg2  = (int*)w2;   w2 += sizeof(int) * (size_t)N;
        int*   sdeg2  = (int*)w2;   w2 += sizeof(int) * (size_t)M;
        float* isd_u2 = (float*)w2; w2 += sizeof(float) * (size_t)N;
        float* isd_s2 = (float*)w2; w2 += sizeof(float) * (size_t)M;
        if ((size_t)(w2 - (char*)d_ws) <= ws_size) {
            hipMemsetAsync(udeg2, 0, sizeof(int) * (size_t)(N + M), stream);
            deg_kernel<<<(E + 255) / 256, 256, 0, stream>>>(u, s, E, udeg2, sdeg2);
            init_isd_kernel<<<(nm + 255) / 256, 256, 0, stream>>>(
                udeg2, sdeg2, isd_u2, isd_s2, N, M);
            hipMemsetAsync(d_out, 0, sizeof(float) * (size_t)out_size, stream);
            scatter_kernel<<<((size_t)E + 3) / 4, 256, 0, stream>>>(
                spot_x, user_x, u, s, E, isd_u2, isd_s2, spot_out, user_out);
        }
    }
}